// Round 1
// baseline (148.025 us; speedup 1.0000x reference)
//
#include <hip/hip_runtime.h>
#include <math.h>

#define Bsz  2
#define Cch  16
#define Hdim 256
#define Wdim 256
#define HW   (Hdim * Wdim)
#define CctxN 64

// Kernel 1: q,k,v projections. One thread per (b, h*W+w).
__global__ __launch_bounds__(256) void qkv_kernel(
    const float* __restrict__ x, const float* __restrict__ y,
    const float* __restrict__ Wq, const float* __restrict__ bq,
    const float* __restrict__ Wk, const float* __restrict__ bk,
    const float* __restrict__ Wv, const float* __restrict__ bv,
    float* __restrict__ q, float* __restrict__ k, float* __restrict__ v) {
  int idx = blockIdx.x * blockDim.x + threadIdx.x;   // 0 .. B*HW-1
  int b  = idx >> 16;
  int hw = idx & (HW - 1);
  const float* xp = x + (size_t)b * Cch * HW + hw;
  float q0 = bq[0], q1 = bq[1], k0 = bk[0], k1 = bk[1];
#pragma unroll
  for (int c = 0; c < Cch; c++) {
    float xv = xp[c * HW];
    q0 = fmaf(Wq[c],       xv, q0);
    q1 = fmaf(Wq[Cch + c], xv, q1);
    k0 = fmaf(Wk[c],       xv, k0);
    k1 = fmaf(Wk[Cch + c], xv, k1);
  }
  q[(size_t)(b * 2 + 0) * HW + hw] = q0;
  q[(size_t)(b * 2 + 1) * HW + hw] = q1;
  k[(size_t)(b * 2 + 0) * HW + hw] = k0;
  k[(size_t)(b * 2 + 1) * HW + hw] = k1;
  const float* yp = y + (size_t)b * CctxN * HW + hw;
  float vv = bv[0];
#pragma unroll
  for (int c = 0; c < CctxN; c++) vv = fmaf(Wv[c], yp[c * HW], vv);
  v[(size_t)b * HW + hw] = vv;
}

// Kernel 2: fused criss-cross attention with online softmax.
// Block = (b,h); thread = w. Row k/v in LDS; column k/v coalesced from L2.
__global__ __launch_bounds__(256) void attn_kernel(
    const float* __restrict__ x, const float* __restrict__ q,
    const float* __restrict__ k, const float* __restrict__ v,
    const float* __restrict__ gamma, float* __restrict__ out) {
  int b = blockIdx.x >> 8;
  int h = blockIdx.x & 255;
  int w = threadIdx.x;

  __shared__ float krow0[Wdim], krow1[Wdim], vrow[Wdim];
  const float* kb = k + (size_t)b * 2 * HW;
  const float* vb = v + (size_t)b * HW;
  krow0[w] = kb[h * Wdim + w];
  krow1[w] = kb[HW + h * Wdim + w];
  vrow[w]  = vb[h * Wdim + w];
  __syncthreads();

  float q0 = q[(size_t)(b * 2 + 0) * HW + h * Wdim + w];
  float q1 = q[(size_t)(b * 2 + 1) * HW + h * Wdim + w];
  const float* kc0 = kb + w;        // stride Wdim over g  (coalesced per-g)
  const float* kc1 = kb + HW + w;
  const float* vc  = vb + w;

  // Online softmax over the 512 joint scores (eH with diag mask, then eW).
  float m = -1e30f, Z = 0.f, numH = 0.f, numW = 0.f;
#pragma unroll 4
  for (int g = 0; g < Hdim; g++) {
    float kh0 = kc0[g * Wdim];
    float kh1 = kc1[g * Wdim];
    float vcg = vc[g * Wdim];
    float eH = fmaf(q0, kh0, q1 * kh1);
    float eW = fmaf(q0, krow0[g], q1 * krow1[g]);
    bool diag = (g == h);
    float eHm = diag ? -1e30f : eH;
    float mn = fmaxf(m, fmaxf(eHm, eW));
    float sc = __expf(m - mn);         // first iter: exp(-huge) = 0
    float pH = diag ? 0.f : __expf(eH - mn);
    float pW = __expf(eW - mn);
    Z    = fmaf(Z,    sc, pH + pW);
    numH = fmaf(numH, sc, pH * vcg);
    numW = fmaf(numW, sc, pW * vrow[g]);
    m = mn;
  }
  float s = gamma[0] * (numH + numW) / Z;

  size_t base = (size_t)b * Cch * HW + h * Wdim + w;
#pragma unroll
  for (int c = 0; c < Cch; c++) out[base + c * HW] = s + x[base + c * HW];
}

extern "C" void kernel_launch(void* const* d_in, const int* in_sizes, int n_in,
                              void* d_out, int out_size, void* d_ws, size_t ws_size,
                              hipStream_t stream) {
  const float* x     = (const float*)d_in[0];
  const float* y     = (const float*)d_in[1];
  const float* Wq    = (const float*)d_in[2];
  const float* bq    = (const float*)d_in[3];
  const float* Wk    = (const float*)d_in[4];
  const float* bk    = (const float*)d_in[5];
  const float* Wv    = (const float*)d_in[6];
  const float* bv    = (const float*)d_in[7];
  const float* gamma = (const float*)d_in[8];
  float* out = (float*)d_out;

  float* ws = (float*)d_ws;
  float* q = ws;                      // B*2*HW = 262144 floats
  float* k = ws + Bsz * 2 * HW;       // B*2*HW
  float* v = ws + 2 * Bsz * 2 * HW;   // B*HW  (total 2.62 MB)

  qkv_kernel<<<Bsz * HW / 256, 256, 0, stream>>>(x, y, Wq, bq, Wk, bk, Wv, bv, q, k, v);
  attn_kernel<<<Bsz * Hdim, 256, 0, stream>>>(x, q, k, v, gamma, out);
}

// Round 3
// 142.435 us; speedup vs baseline: 1.0392x; 1.0392x over previous
//
#include <hip/hip_runtime.h>
#include <math.h>

#define Bsz  2
#define Cch  16
#define Hdim 256
#define Wdim 256
#define HW   (Hdim * Wdim)
#define BHW  (Bsz * HW)
#define CctxN 64
#define NS   8            // g-segments per (b, h-tile)
#define SG   (Hdim / NS)  // 32 g values per segment
#define TH   4            // h rows per block
#define LOG2E 1.44269504088896340736f

// exp2f lowers to v_exp_f32 on amdgcn (HW exp is base-2).
__device__ __forceinline__ float fexp2(float x) { return exp2f(x); }

// Kernel 1: q,k,v projections. q pre-scaled by log2(e); q,k packed as float2.
__global__ __launch_bounds__(256) void qkv_kernel(
    const float* __restrict__ x, const float* __restrict__ y,
    const float* __restrict__ Wq, const float* __restrict__ bq,
    const float* __restrict__ Wk, const float* __restrict__ bk,
    const float* __restrict__ Wv, const float* __restrict__ bv,
    float2* __restrict__ qpk, float2* __restrict__ kpk, float* __restrict__ v) {
  int idx = blockIdx.x * blockDim.x + threadIdx.x;   // b*HW + hw
  int b  = idx >> 16;
  int hw = idx & (HW - 1);
  const float* xp = x + (size_t)b * Cch * HW + hw;
  float q0 = bq[0], q1 = bq[1], k0 = bk[0], k1 = bk[1];
#pragma unroll
  for (int c = 0; c < Cch; c++) {
    float xv = xp[c * HW];
    q0 = fmaf(Wq[c],       xv, q0);
    q1 = fmaf(Wq[Cch + c], xv, q1);
    k0 = fmaf(Wk[c],       xv, k0);
    k1 = fmaf(Wk[Cch + c], xv, k1);
  }
  qpk[idx] = make_float2(q0 * LOG2E, q1 * LOG2E);  // exp(e) == exp2((q*log2e)·k)
  kpk[idx] = make_float2(k0, k1);
  const float* yp = y + (size_t)b * CctxN * HW + hw;
  float vv = bv[0];
#pragma unroll
  for (int c = 0; c < CctxN; c++) vv = fmaf(Wv[c], yp[c * HW], vv);
  v[idx] = vv;
}

// Kernel 2: partial criss-cross softmax sums (no max-sub: scores bounded).
// Block = (b, h-tile of TH, g-segment of SG). Thread = w. Column k/v loads
// shared across TH h-rows in registers; row (k0,k1,v) in LDS float4 broadcast.
__global__ __launch_bounds__(256, 4) void attn_kernel(
    const float2* __restrict__ qpk, const float2* __restrict__ kpk,
    const float* __restrict__ v, float* __restrict__ part) {
  int s  = blockIdx.x & (NS - 1);
  int ht = (blockIdx.x >> 3) & 63;    // Hdim/TH = 64
  int b  = blockIdx.x >> 9;
  int w  = threadIdx.x;
  int h0 = ht * TH;
  int g0 = s * SG;
  size_t bbase = (size_t)b * HW;

  __shared__ float4 rowpk[TH][SG];    // (k0, k1, v, -) for row h0+h_l, pos g0+gg
  if (threadIdx.x < TH * SG) {
    int h_l = threadIdx.x >> 5, gg = threadIdx.x & 31;
    size_t ridx = bbase + (size_t)(h0 + h_l) * Wdim + g0 + gg;
    float2 kk = kpk[ridx];
    rowpk[h_l][gg] = make_float4(kk.x, kk.y, v[ridx], 0.f);
  }
  float q0[TH], q1[TH];
#pragma unroll
  for (int h_l = 0; h_l < TH; h_l++) {
    float2 qq = qpk[bbase + (size_t)(h0 + h_l) * Wdim + w];
    q0[h_l] = qq.x; q1[h_l] = qq.y;
  }
  __syncthreads();

  float Z[TH] = {0,0,0,0}, nH[TH] = {0,0,0,0}, nW[TH] = {0,0,0,0};
#pragma unroll 4
  for (int gg = 0; gg < SG; gg++) {
    int g = g0 + gg;
    float2 kc = kpk[bbase + (size_t)g * Wdim + w];
    float  vc = v  [bbase + (size_t)g * Wdim + w];
#pragma unroll
    for (int h_l = 0; h_l < TH; h_l++) {
      float4 r = rowpk[h_l][gg];
      float eH = fmaf(q0[h_l], kc.x, q1[h_l] * kc.y);
      float eW = fmaf(q0[h_l], r.x,  q1[h_l] * r.y);
      float pH = (g == h0 + h_l) ? 0.f : fexp2(eH);   // diagonal mask
      float pW = fexp2(eW);
      Z [h_l] += pH + pW;
      nH[h_l] = fmaf(pH, vc,  nH[h_l]);
      nW[h_l] = fmaf(pW, r.z, nW[h_l]);
    }
  }
#pragma unroll
  for (int h_l = 0; h_l < TH; h_l++) {
    size_t idx = bbase + (size_t)(h0 + h_l) * Wdim + w;
    part[(size_t)(s * 3 + 0) * BHW + idx] = Z [h_l];
    part[(size_t)(s * 3 + 1) * BHW + idx] = nH[h_l];
    part[(size_t)(s * 3 + 2) * BHW + idx] = nW[h_l];
  }
}

// Kernel 3: merge NS partials, finalize softmax, add residual, broadcast 16ch.
__global__ __launch_bounds__(256) void epi_kernel(
    const float* __restrict__ x, const float* __restrict__ part,
    const float* __restrict__ gamma, float* __restrict__ out) {
  int idx = blockIdx.x * blockDim.x + threadIdx.x;   // 0..BHW-1
  float Z = 0.f, nH = 0.f, nW = 0.f;
#pragma unroll
  for (int s2 = 0; s2 < NS; s2++) {
    Z  += part[(size_t)(s2 * 3 + 0) * BHW + idx];
    nH += part[(size_t)(s2 * 3 + 1) * BHW + idx];
    nW += part[(size_t)(s2 * 3 + 2) * BHW + idx];
  }
  float sv = gamma[0] * (nH + nW) / Z;
  int b = idx >> 16, hw = idx & (HW - 1);
  size_t base = (size_t)b * Cch * HW + hw;
#pragma unroll
  for (int c = 0; c < Cch; c++) out[base + c * HW] = sv + x[base + c * HW];
}

extern "C" void kernel_launch(void* const* d_in, const int* in_sizes, int n_in,
                              void* d_out, int out_size, void* d_ws, size_t ws_size,
                              hipStream_t stream) {
  const float* x     = (const float*)d_in[0];
  const float* y     = (const float*)d_in[1];
  const float* Wq    = (const float*)d_in[2];
  const float* bq    = (const float*)d_in[3];
  const float* Wk    = (const float*)d_in[4];
  const float* bk    = (const float*)d_in[5];
  const float* Wv    = (const float*)d_in[6];
  const float* bv    = (const float*)d_in[7];
  const float* gamma = (const float*)d_in[8];
  float* out = (float*)d_out;

  float* ws = (float*)d_ws;
  float2* qpk = (float2*)ws;                 // BHW float2
  float2* kpk = (float2*)(ws + 2 * BHW);     // BHW float2
  float*  v   = ws + 4 * BHW;                // BHW floats
  float*  part = ws + 5 * BHW;               // 3*NS*BHW floats (~12.6 MB)

  qkv_kernel<<<BHW / 256, 256, 0, stream>>>(x, y, Wq, bq, Wk, bk, Wv, bv, qpk, kpk, v);
  attn_kernel<<<Bsz * (Hdim / TH) * NS, 256, 0, stream>>>(qpk, kpk, v, part);
  epi_kernel<<<BHW / 256, 256, 0, stream>>>(x, part, gamma, out);
}

// Round 4
// 129.436 us; speedup vs baseline: 1.1436x; 1.1004x over previous
//
#include <hip/hip_runtime.h>
#include <math.h>

#define Bsz  2
#define Cch  16
#define Hdim 256
#define Wdim 256
#define HW   (Hdim * Wdim)
#define BHW  (Bsz * HW)
#define CctxN 64
#define NS   4            // g-segments
#define SG   (Hdim / NS)  // 64 g values per segment
#define TH   4            // h rows per block
#define LOG2E 1.44269504088896340736f

// exp2f lowers to v_exp_f32 on amdgcn (HW exp is base-2).
__device__ __forceinline__ float fexp2(float x) { return exp2f(x); }

// Kernel 1: projections. 2 hw per thread, float2 loads. q pre-scaled by log2e.
// kv packs (k0, k1, v, 0) per position for one-dwordx4 column loads in attn.
__global__ __launch_bounds__(256) void qkv_kernel(
    const float* __restrict__ x, const float* __restrict__ y,
    const float* __restrict__ Wq, const float* __restrict__ bq,
    const float* __restrict__ Wk, const float* __restrict__ bk,
    const float* __restrict__ Wv, const float* __restrict__ bv,
    float2* __restrict__ qpk, float4* __restrict__ kv) {
  int idx0 = (blockIdx.x * blockDim.x + threadIdx.x) * 2;  // b*HW + hw, even
  int b  = idx0 >> 16;
  int hw = idx0 & (HW - 1);
  const float2* xp = (const float2*)(x + (size_t)b * Cch * HW + hw);
  float q0a = bq[0], q1a = bq[1], k0a = bk[0], k1a = bk[1];
  float q0b = bq[0], q1b = bq[1], k0b = bk[0], k1b = bk[1];
#pragma unroll
  for (int c = 0; c < Cch; c++) {
    float2 xv = xp[c * (HW / 2)];
    q0a = fmaf(Wq[c],       xv.x, q0a);  q0b = fmaf(Wq[c],       xv.y, q0b);
    q1a = fmaf(Wq[Cch + c], xv.x, q1a);  q1b = fmaf(Wq[Cch + c], xv.y, q1b);
    k0a = fmaf(Wk[c],       xv.x, k0a);  k0b = fmaf(Wk[c],       xv.y, k0b);
    k1a = fmaf(Wk[Cch + c], xv.x, k1a);  k1b = fmaf(Wk[Cch + c], xv.y, k1b);
  }
  qpk[idx0]     = make_float2(q0a * LOG2E, q1a * LOG2E);
  qpk[idx0 + 1] = make_float2(q0b * LOG2E, q1b * LOG2E);
  const float2* yp = (const float2*)(y + (size_t)b * CctxN * HW + hw);
  float va = bv[0], vb2 = bv[0];
#pragma unroll
  for (int c = 0; c < CctxN; c++) {
    float2 yv = yp[c * (HW / 2)];
    va  = fmaf(Wv[c], yv.x, va);
    vb2 = fmaf(Wv[c], yv.y, vb2);
  }
  kv[idx0]     = make_float4(k0a, k1a, va,  0.f);
  kv[idx0 + 1] = make_float4(k0b, k1b, vb2, 0.f);
}

// Kernel 2: partial criss-cross softmax sums (no max-sub: scores bounded).
// Block = (b, h-tile of TH, g-segment of SG). Thread = w. Diagonal handled by
// post-loop subtraction (no per-iter mask). Row kv in LDS (broadcast reads).
__global__ __launch_bounds__(256) void attn_kernel(
    const float2* __restrict__ qpk, const float4* __restrict__ kv,
    float* __restrict__ part) {
  int s  = blockIdx.x & (NS - 1);
  int ht = (blockIdx.x >> 2) & 63;    // Hdim/TH = 64
  int b  = blockIdx.x >> 8;
  int w  = threadIdx.x;
  int h0 = ht * TH;
  int g0 = s * SG;
  size_t bbase = (size_t)b * HW;

  __shared__ float4 rowkv[TH][SG];
  {
    int h_l = threadIdx.x >> 6, gg = threadIdx.x & 63;  // TH*SG == 256
    rowkv[h_l][gg] = kv[bbase + (size_t)(h0 + h_l) * Wdim + g0 + gg];
  }
  float q0[TH], q1[TH];
#pragma unroll
  for (int h_l = 0; h_l < TH; h_l++) {
    float2 qq = qpk[bbase + (size_t)(h0 + h_l) * Wdim + w];
    q0[h_l] = qq.x; q1[h_l] = qq.y;
  }
  __syncthreads();

  float Z[TH] = {0,0,0,0}, nH[TH] = {0,0,0,0}, nW[TH] = {0,0,0,0};
#pragma unroll 4
  for (int gg = 0; gg < SG; gg++) {
    float4 kc = kv[bbase + (size_t)(g0 + gg) * Wdim + w];
#pragma unroll
    for (int h_l = 0; h_l < TH; h_l++) {
      float4 r = rowkv[h_l][gg];
      float pH = fexp2(fmaf(q0[h_l], kc.x, q1[h_l] * kc.y));
      float pW = fexp2(fmaf(q0[h_l], r.x,  q1[h_l] * r.y));
      Z [h_l] += pH + pW;
      nH[h_l] = fmaf(pH, kc.z, nH[h_l]);
      nW[h_l] = fmaf(pW, r.z,  nW[h_l]);
    }
  }
  // Diagonal fixup: subtract the g==h term (whole h-tile lies in one segment).
  if ((h0 >> 6) == s) {
#pragma unroll
    for (int h_l = 0; h_l < TH; h_l++) {
      float4 kd = kv[bbase + (size_t)(h0 + h_l) * Wdim + w];
      float pd = fexp2(fmaf(q0[h_l], kd.x, q1[h_l] * kd.y));
      Z [h_l] -= pd;
      nH[h_l] = fmaf(-pd, kd.z, nH[h_l]);
    }
  }
#pragma unroll
  for (int h_l = 0; h_l < TH; h_l++) {
    size_t idx = bbase + (size_t)(h0 + h_l) * Wdim + w;
    part[(size_t)(s * 3 + 0) * BHW + idx] = Z [h_l];
    part[(size_t)(s * 3 + 1) * BHW + idx] = nH[h_l];
    part[(size_t)(s * 3 + 2) * BHW + idx] = nW[h_l];
  }
}

// Kernel 3: merge NS partials, finalize, residual add, broadcast 16 channels.
// 2 hw per thread, float2 traffic.
__global__ __launch_bounds__(256) void epi_kernel(
    const float* __restrict__ x, const float* __restrict__ part,
    const float* __restrict__ gamma, float* __restrict__ out) {
  int idx0 = (blockIdx.x * blockDim.x + threadIdx.x) * 2;
  float2 Z = make_float2(0.f, 0.f), nH = Z, nW = Z;
#pragma unroll
  for (int s2 = 0; s2 < NS; s2++) {
    float2 a = *(const float2*)&part[(size_t)(s2 * 3 + 0) * BHW + idx0];
    float2 c = *(const float2*)&part[(size_t)(s2 * 3 + 1) * BHW + idx0];
    float2 d = *(const float2*)&part[(size_t)(s2 * 3 + 2) * BHW + idx0];
    Z.x += a.x;  Z.y += a.y;
    nH.x += c.x; nH.y += c.y;
    nW.x += d.x; nW.y += d.y;
  }
  float g = gamma[0];
  float2 sv = make_float2(g * (nH.x + nW.x) / Z.x, g * (nH.y + nW.y) / Z.y);
  int b = idx0 >> 16, hw = idx0 & (HW - 1);
  size_t base = (size_t)b * Cch * HW + hw;
#pragma unroll
  for (int c = 0; c < Cch; c++) {
    float2 xv = *(const float2*)&x[base + c * HW];
    *(float2*)&out[base + c * HW] = make_float2(sv.x + xv.x, sv.y + xv.y);
  }
}

extern "C" void kernel_launch(void* const* d_in, const int* in_sizes, int n_in,
                              void* d_out, int out_size, void* d_ws, size_t ws_size,
                              hipStream_t stream) {
  const float* x     = (const float*)d_in[0];
  const float* y     = (const float*)d_in[1];
  const float* Wq    = (const float*)d_in[2];
  const float* bq    = (const float*)d_in[3];
  const float* Wk    = (const float*)d_in[4];
  const float* bk    = (const float*)d_in[5];
  const float* Wv    = (const float*)d_in[6];
  const float* bv    = (const float*)d_in[7];
  const float* gamma = (const float*)d_in[8];
  float* out = (float*)d_out;

  float* ws = (float*)d_ws;
  float2* qpk = (float2*)ws;                  // BHW float2 (1 MB)
  float4* kv  = (float4*)(ws + 2 * BHW);      // BHW float4 (2 MB)
  float*  part = ws + 6 * BHW;                // 3*NS*BHW floats (6.3 MB)

  qkv_kernel<<<BHW / 512, 256, 0, stream>>>(x, y, Wq, bq, Wk, bk, Wv, bv, qpk, kv);
  attn_kernel<<<Bsz * (Hdim / TH) * NS, 256, 0, stream>>>(qpk, kv, part);
  epi_kernel<<<BHW / 512, 256, 0, stream>>>(x, part, gamma, out);
}